// Round 8
// baseline (257.111 us; speedup 1.0000x reference)
//
#include <hip/hip_runtime.h>

// OHEM loss, specialized for NUM_CLASSES == 1:
//   ce == 0 exactly -> cls_loss == 0, hard-negative mining dead.
//   out = 0.2 * sum_{pos} smooth_l1(loc_preds - loc_targets) / num_pos
//
// Round 7 (resubmit after GPU acquisition timeout).
// Rounds 1/2/5 all pinned at ~44G cache-lines/s (2.7-2.9 TB/s effective)
// regardless of ILP/coalescing -> line-request-rate cap.
// Lever: fetch FEWER lines. One thread = one 64B line (2 anchors); if both
// anchors are negative (P~0.25) skip the 8 loc float4 loads entirely
// (exec-masked lanes fetch nothing). Also: per-wave partials written
// directly (no LDS / __syncthreads) so waves retire independently.

constexpr int BLK = 256;
constexpr int WPB = BLK / 64;   // waves per block

__device__ __forceinline__ float sl1(float d) {
    float ax = fabsf(d);
    return (ax < 1.0f) ? 0.5f * d * d : ax - 0.5f;
}

__device__ __forceinline__ float sl1x8(const float4& p0, const float4& p1,
                                       const float4& q0, const float4& q1) {
    return sl1(p0.x - q0.x) + sl1(p0.y - q0.y) + sl1(p0.z - q0.z) + sl1(p0.w - q0.w)
         + sl1(p1.x - q1.x) + sl1(p1.y - q1.y) + sl1(p1.z - q1.z) + sl1(p1.w - q1.w);
}

__global__ __launch_bounds__(BLK) void ohem_partial(
        const float4* __restrict__ p4,     // [n_pair*4] float4 (64B per pair)
        const float4* __restrict__ t4,
        const int2*   __restrict__ cls2,   // [n_pair] int2
        double* __restrict__ wsum,         // [nblk*WPB] per-wave partials
        int*    __restrict__ wcnt,
        int n_pair)
{
    const int t = blockIdx.x * BLK + threadIdx.x;   // line index (2 anchors)
    float s = 0.0f;
    int cnt = 0;
    if (t < n_pair) {
        const int2 c = cls2[t];
        cnt = (c.x > 0) + (c.y > 0);
        if (cnt) {
            // only lanes owning a line with >=1 positive anchor fetch it
            const int b = t * 4;
            float4 p0 = p4[b + 0], p1 = p4[b + 1], p2 = p4[b + 2], p3 = p4[b + 3];
            float4 q0 = t4[b + 0], q1 = t4[b + 1], q2 = t4[b + 2], q3 = t4[b + 3];
            const float s0 = sl1x8(p0, p1, q0, q1);
            const float s1 = sl1x8(p2, p3, q2, q3);
            s = ((c.x > 0) ? s0 : 0.0f) + ((c.y > 0) ? s1 : 0.0f);
        }
    }
    // wave-64 reduce; f64 from here (absmax 0.0 with this tree in r1/r5)
    double acc = (double)s;
    #pragma unroll
    for (int off = 32; off > 0; off >>= 1) {
        acc += __shfl_down(acc, off, 64);
        cnt += __shfl_down(cnt, off, 64);
    }
    if ((threadIdx.x & 63) == 0) {
        const int w = blockIdx.x * WPB + (threadIdx.x >> 6);
        wsum[w] = acc;
        wcnt[w] = cnt;
    }
}

__global__ __launch_bounds__(BLK) void ohem_final(
        const double* __restrict__ wsum,
        const int*    __restrict__ wcnt,
        float* __restrict__ out, int n_w)
{
    double acc = 0.0;
    long long cnt = 0;
    for (int i = threadIdx.x; i < n_w; i += BLK) {
        acc += wsum[i];
        cnt += wcnt[i];
    }
    #pragma unroll
    for (int off = 32; off > 0; off >>= 1) {
        acc += __shfl_down(acc, off, 64);
        cnt += __shfl_down(cnt, off, 64);
    }
    __shared__ double    ssum[WPB];
    __shared__ long long scnt[WPB];
    const int lane = threadIdx.x & 63;
    const int wid  = threadIdx.x >> 6;
    if (lane == 0) { ssum[wid] = acc; scnt[wid] = cnt; }
    __syncthreads();
    if (threadIdx.x == 0) {
        double a = 0.0; long long c = 0;
        #pragma unroll
        for (int w = 0; w < WPB; ++w) { a += ssum[w]; c += scnt[w]; }
        out[0] = (float)(0.2 * a / (double)c);
    }
}

extern "C" void kernel_launch(void* const* d_in, const int* in_sizes, int n_in,
                              void* d_out, int out_size, void* d_ws, size_t ws_size,
                              hipStream_t stream) {
    const float4* p4   = (const float4*)d_in[0];  // [B, A, 8] f32
    const float4* t4   = (const float4*)d_in[1];
    // d_in[2] (cls_preds) provably unused: ce == 0 when C == 1.
    const int2*   cls2 = (const int2*)d_in[3];    // [B, A] i32, 2 anchors/thread
    const int n_anchor = in_sizes[3];             // 3,200,000
    const int n_pair   = n_anchor / 2;            // 1,600,000 lines
    const int nblk     = (n_pair + BLK - 1) / BLK;// 6250, exact cover
    const int n_w      = nblk * WPB;              // 25,000 wave partials

    double* wsum = (double*)d_ws;
    int*    wcnt = (int*)((char*)d_ws + (size_t)n_w * sizeof(double));

    ohem_partial<<<nblk, BLK, 0, stream>>>(p4, t4, cls2, wsum, wcnt, n_pair);
    ohem_final<<<1, BLK, 0, stream>>>(wsum, wcnt, (float*)d_out, n_w);
}